// Round 14
// baseline (84.587 us; speedup 1.0000x reference)
//
#include <hip/hip_runtime.h>
#include <math.h>

// QNN: 8 qubits, DIM=256, 2 entangling layers, B samples.
//  - RX(x_q) fuses with layer-1 RX -> product state v_q (V0,V1).
//  - CNOT ring 1 folded into product expansion; rank-8 split (R7/R9):
//      S[row][col] = RF[row] * TH[(h1,h1^h0)][col0] * TC[col][r0]
//  - Layer-2: phi = A*S*B^T computed as T = S^T*A^T then phi^T = B*T with
//    mfma_f32_16x16x16f16 (R12): operand layout == C/D layout, zero LDS
//    round-trips in the matmul.
//  - CNOT ring 2 + <Z_w> + reduction folded into a constant sign matrix
//    applied as mfma 16x16x32 f16 chain (R6), phi^T bit mapping (R12).
// R14: stall-bound fix (issue util ~12% by static count): batch the 4
//      samples' table loads per h-group (1 wait-batch, not 4 serial stalls),
//      batch epilogue R reads, split epilogue accumulator into 2 independent
//      4-deep MFMA chains + add (halves ~200cyc serial tail). Same math.

typedef float f2 __attribute__((ext_vector_type(2)));
typedef float f4 __attribute__((ext_vector_type(4)));
typedef _Float16 half4 __attribute__((ext_vector_type(4)));
typedef _Float16 half8 __attribute__((ext_vector_type(8)));

// f32 complex mul, 2 VOP3P ops (verified R3-R13) - table-build phase
__device__ __forceinline__ f2 cmul_pk(f2 a, f2 b) {
    f2 t, d;
    asm("v_pk_mul_f32 %0, %1, %2 op_sel:[0,0] op_sel_hi:[0,1]"
        : "=v"(t) : "v"(a), "v"(b));
    asm("v_pk_fma_f32 %0, %1, %2, %3 op_sel:[1,1,0] op_sel_hi:[1,0,1] neg_lo:[1,0,0] neg_hi:[0,0,0]"
        : "=v"(d) : "v"(a), "v"(b), "v"(t));
    return d;
}
// packed-f16 complex mul (verified R9-R13)
__device__ __forceinline__ unsigned cmulh(unsigned a, unsigned b) {
    unsigned t, d;
    asm("v_pk_mul_f16 %0, %1, %2 op_sel:[0,0] op_sel_hi:[0,1]"
        : "=v"(t) : "v"(a), "v"(b));
    asm("v_pk_fma_f16 %0, %1, %2, %3 op_sel:[1,1,0] op_sel_hi:[1,0,1] neg_lo:[1,0,0] neg_hi:[0,0,0]"
        : "=v"(d) : "v"(a), "v"(b), "v"(t));
    return d;
}
__device__ __forceinline__ unsigned pkh(f2 v) {
    auto pk = __builtin_amdgcn_cvt_pkrtz(v.x, v.y);
    unsigned u; __builtin_memcpy(&u, &pk, 4);
    return u;
}
__device__ __forceinline__ half4 h4(uint2 u) {
    half4 h; __builtin_memcpy(&h, &u, 8);
    return h;
}
__device__ __forceinline__ f4 mfma16(half4 a, half4 b, f4 c) {
    return __builtin_amdgcn_mfma_f32_16x16x16f16(a, b, c, 0, 0, 0);
}

// ---------------- setup (identical to R12/R13) ----------------
__global__ void qnn_setup(const float* __restrict__ w, float* __restrict__ p) {
    int t = threadIdx.x;
    if (t < 8) {
        int q = t;
        float cb = cosf(w[q*3+1]*0.5f), sb = sinf(w[q*3+1]*0.5f);
        float cg = cosf(w[q*3+2]*0.5f), sg = sinf(w[q*3+2]*0.5f);
        p[q] = w[q*3+0];
        float* K = p + 8 + q*8;
        K[0] = cg*cb;  K[1] = -sg*cb;      // K1
        K[2] = sg*sb;  K[3] = cg*sb;       // K2
        K[4] = cg*sb;  K[5] = sg*sb;       // K3
        K[6] = sg*cb;  K[7] = -cg*cb;      // K4
    }
    float G[8][2][2][2];
    for (int q = 0; q < 8; ++q) {
        const float* wq = w + (8+q)*3;
        float ca = cosf(wq[0]*0.5f), sa = sinf(wq[0]*0.5f);
        float cb = cosf(wq[1]*0.5f), sb = sinf(wq[1]*0.5f);
        float cg = cosf(wq[2]*0.5f), sg = sinf(wq[2]*0.5f);
        float A = cb*ca, Bv = sb*sa, C = sb*ca, D = cb*sa;
        float g00r = cg*A + sg*Bv, g00i = cg*Bv - sg*A;
        float g01r = -(cg*C + sg*D), g01i = sg*C - cg*D;
        G[q][0][0][0]=g00r;  G[q][0][0][1]=g00i;
        G[q][0][1][0]=g01r;  G[q][0][1][1]=g01i;
        G[q][1][0][0]=-g01r; G[q][1][0][1]=g01i;
        G[q][1][1][0]=g00r;  G[q][1][1][1]=-g00i;
    }
    int m = t & 15, k2 = t >> 4;
    float ar = 1.f, ai = 0.f, br = 1.f, bi = 0.f;
    for (int j = 0; j < 4; ++j) {
        int bm = (m >> (3-j)) & 1, bk = (k2 >> (3-j)) & 1;
        float gr = G[j][bm][bk][0],  gi = G[j][bm][bk][1];
        float nr = ar*gr - ai*gi, ni = ar*gi + ai*gr; ar = nr; ai = ni;
        float hr = G[4+j][bm][bk][0], hi = G[4+j][bm][bk][1];
        float mr = br*hr - bi*hi, mi = br*hi + bi*hr; br = mr; bi = mi;
    }
    _Float16* S1Ar  = (_Float16*)((char*)p +  512);
    _Float16* S1Ai  = (_Float16*)((char*)p + 1024);
    _Float16* S1nAi = (_Float16*)((char*)p + 1536);
    _Float16* S2Br  = (_Float16*)((char*)p + 2048);
    _Float16* S2Bi  = (_Float16*)((char*)p + 2560);
    _Float16* S2nBi = (_Float16*)((char*)p + 3072);
    int idx = ((k2 >> 2)*16 + m)*4 + (k2 & 3);
    S1Ar[idx]  = (_Float16)ar;
    S1Ai[idx]  = (_Float16)ai;
    S1nAi[idx] = (_Float16)(-ai);
    S2Br[idx]  = (_Float16)br;
    S2Bi[idx]  = (_Float16)bi;
    S2nBi[idx] = (_Float16)(-bi);

    // sign table - phi^T bit assignment (R12, verified):
    const int cls[8] = {2, 0, 0, 0, 0, 0, 1, 2};
    const int msk[8] = {55, 12, 14, 15, 47, 63, 63, 63};
    _Float16* SG = (_Float16*)((char*)p + 4608);
    for (int e = t; e < 512; e += 256) {
        int tt = e >> 6, l = e & 63, n = l & 15, quad = l >> 4;
        for (int j = 0; j < 8; ++j) {
            int k  = tt*32 + quad*8 + j;
            int Lp = k >> 2, c = k & 3;
            float v = 0.f;
            if (n < 8 && c == cls[n])
                v = (__popc(msk[n] & Lp) & 1) ? -1.f : 1.f;
            SG[e*8 + j] = (_Float16)v;
        }
    }
}

// per-wave LDS (5888 B -> 6144; block 24576 -> 6 blocks/CU):
//   TH 512 | TC 2176 (stride 136) | RF 1024 (stride 64) |
//   R 2176 (4 rows x 544)  [VT 2048 aliased into R, dead before R writes]
#define WAVE_LDS 6144

__global__ __launch_bounds__(256, 6) void qnn_main(
        const float* __restrict__ x, const float* __restrict__ p,
        float* __restrict__ out, int B)
{
    __shared__ __align__(16) char smem[4 * WAVE_LDS];
    const int lane = threadIdx.x & 63;
    const int wid  = threadIdx.x >> 6;
    const int L = lane;
    const int b0 = (blockIdx.x * 4 + wid) * 16;
    if (b0 >= B) return;

    char* wb  = smem + wid * WAVE_LDS;
    char* THb = wb;                     // 512
    char* TCb = wb + 512;               // 2176
    char* RFb = wb + 2688;              // 1024
    char* Rb  = wb + 3712;              // 2176 (VT alias first)
    f4*   VT  = (f4*)Rb;

    // constant frags (loop-invariant), all f16
    const uint2* ft = (const uint2*)((const char*)p + 512);
    half4 Art  = h4(ft[      L]);
    half4 Ait  = h4(ft[ 64 + L]);
    half4 nAit = h4(ft[128 + L]);
    half4 Brf  = h4(ft[192 + L]);
    half4 Bif  = h4(ft[256 + L]);
    half4 nBif = h4(ft[320 + L]);
    const half8* sgt = (const half8*)((const char*)p + 4608);

    // ---- phase A: build V for 16 samples x 8 qubits (2 builds/lane) ----
    {
        int sI = L >> 2, qp = (L & 3) * 2;
        float2 xv  = ((const float2*)x)[(size_t)(b0 + sI)*4 + (L & 3)];
        float2 w0p = ((const float2*)p)[qp >> 1];
        const f4* Kt = (const f4*)(p + 8);
#pragma unroll
        for (int u = 0; u < 2; ++u) {
            int q = qp + u;
            float ang = (u ? xv.y : xv.x) + (u ? w0p.y : w0p.x);
            float rev = ang * 0.07957747154594767f;      // (ang/2)/(2pi)
            float ca = __builtin_amdgcn_cosf(rev);
            float sa = __builtin_amdgcn_sinf(rev);
            f4 Ka = Kt[q*2], Kb = Kt[q*2+1];
            f4 v;
            v.x = ca*Ka.x + sa*Ka.z;  v.y = ca*Ka.y + sa*Ka.w;   // V0
            v.z = ca*Kb.x + sa*Kb.z;  v.w = ca*Kb.y + sa*Kb.w;   // V1
            VT[sI*8 + q] = v;
        }
    }
    // same-wave LDS is in-order; all regions per-wave -> no barriers

    // ---- phase B: build TH/TC/RF tables in f16 (4 lanes per sample) ----
    {
        int sI = L >> 2, j = L & 3;
        const f4* Vs = VT + sI*8;
        f4 q0v = Vs[0], q1v = Vs[1], q2v = Vs[2], q3v = Vs[3];
        f4 q4v = Vs[4], q5v = Vs[5], q6v = Vs[6], q7v = Vs[7];
        f2 V0a = {q0v.x,q0v.y}, V0b = {q0v.z,q0v.w};
        f2 V1a = {q1v.x,q1v.y}, V1b = {q1v.z,q1v.w};
        f2 V2a = {q2v.x,q2v.y}, V2b = {q2v.z,q2v.w};
        f2 V3a = {q3v.x,q3v.y}, V3b = {q3v.z,q3v.w};
        f2 V4a = {q4v.x,q4v.y}, V4bv = {q4v.z,q4v.w};
        f2 V5a = {q5v.x,q5v.y}, V5b = {q5v.z,q5v.w};
        f2 V6a = {q6v.x,q6v.y}, V6b = {q6v.z,q6v.w};
        f2 V7a = {q7v.x,q7v.y}, V7b = {q7v.z,q7v.w};
        // TH slot j = (t1,t2) = (j>>1, j&1); entries col0 = 0,1  (f16)
        int t1 = j >> 1, t2 = j & 1;
        f2 th0 = cmul_pk(t1 ? V0b : V0a, t2 ? V1b : V1a);
        f2 th1 = cmul_pk(t1 ? V0a : V0b, t2 ? V1a : V1b);
        *(uint2*)(THb + sI*32 + j*8) = (uint2){pkh(th0), pkh(th1)};
        // TC cols 4j..4j+3 (f16): col3 = j>>1, col2 = j&1 (R9 layout)
        int col3 = j >> 1, col2 = j & 1;
        f2 v5s  = (col3 ^ col2) ? V5b : V5a;
        f2 p6_0 = cmul_pk(v5s, col2 ? V6b : V6a);     // col1 = 0
        f2 p6_1 = cmul_pk(v5s, col2 ? V6a : V6b);     // col1 = 1
        f2 V4lo = col3 ? V4bv : V4a;                  // V4[col3]     (r0=0)
        f2 V4hi = col3 ? V4a : V4bv;                  // V4[1^col3]   (r0=1)
#pragma unroll
        for (int c = 0; c < 4; ++c) {
            int c1 = c >> 1, c0 = c & 1;
            f2 cf = cmul_pk(c1 ? p6_1 : p6_0, (c1 ^ c0) ? V7b : V7a);
            f2 e0 = cmul_pk(cf, V4lo);
            f2 e1 = cmul_pk(cf, V4hi);
            *(uint2*)(TCb + sI*136 + (4*j + c)*8) = (uint2){pkh(e0), pkh(e1)};
        }
        // RF rows 4j..4j+3 (f16): RF[row] = V2[row2^row1]*V3[row1^row0]
        unsigned rr[4];
#pragma unroll
        for (int r = 0; r < 4; ++r) {
            int r1 = r >> 1, r0 = r & 1;
            f2 rf = cmul_pk(((j & 1) ^ r1) ? V2b : V2a, (r1 ^ r0) ? V3b : V3a);
            rr[r] = pkh(rf);
        }
        *(uint4*)(RFb + sI*64 + j*16) = (uint4){rr[0], rr[1], rr[2], rr[3]};
    }

    // ---- hoisted lane constants ----
    const int hq  = L >> 4;             // quad
    const int col = L & 15;
    const int th_t1 = hq >> 1, th_t2 = (hq >> 1) ^ (hq & 1);
    char* THl = THb + ((th_t1*2 + th_t2)*2 + (col & 1))*4;
    char* TCl = TCb + col*8;
    char* RFl = RFb + hq*16;
    char* Rw  = Rb + L*8;
    char* Rr  = Rb + (col & 3)*544 + hq*16;
    const f4 zz = {0.f, 0.f, 0.f, 0.f};

    for (int h = 0; h < 4; ++h) {
        // ---- batched table loads for the 4 samples (one wait-batch) ----
        unsigned uu[4]; uint2 tcc[4]; uint4 rff[4];
#pragma unroll
        for (int s4 = 0; s4 < 4; ++s4) {
            const int s = h*4 + s4;
            uu[s4]  = *(const unsigned*)(THl + s*32);
            tcc[s4] = *(const uint2*)(TCl + s*136);
            rff[s4] = *(const uint4*)(RFl + s*64);
        }
#pragma unroll
        for (int s4 = 0; s4 < 4; ++s4) {
            // ---- front-end: a_r = RF[4hq+r] * (TH*TC[col][r&1]) ----
            unsigned g0 = cmulh(uu[s4], tcc[s4].x);
            unsigned g1 = cmulh(uu[s4], tcc[s4].y);
            unsigned a0 = cmulh(rff[s4].x, g0);
            unsigned a1 = cmulh(rff[s4].y, g1);
            unsigned a2 = cmulh(rff[s4].z, g0);
            unsigned a3 = cmulh(rff[s4].w, g1);
            // a_j = S[quad*4+j][col] = S^T A-operand rows; split re/im
            half4 Srf = h4((uint2){ __builtin_amdgcn_perm(a1, a0, 0x05040100u),
                                    __builtin_amdgcn_perm(a3, a2, 0x05040100u) });
            half4 Sif = h4((uint2){ __builtin_amdgcn_perm(a1, a0, 0x07060302u),
                                    __builtin_amdgcn_perm(a3, a2, 0x07060302u) });
            // ---- stage-1: T = S^T * A^T  (= M^T), 4x mfma 16x16x16 ----
            f4 Tr4 = mfma16(Sif, nAit, mfma16(Srf, Art, zz));
            f4 Ti4 = mfma16(Sif, Art,  mfma16(Srf, Ait, zz));
            half4 Trf = h4((uint2){ pkh((f2){Tr4[0], Tr4[1]}),
                                    pkh((f2){Tr4[2], Tr4[3]}) });
            half4 Tif = h4((uint2){ pkh((f2){Ti4[0], Ti4[1]}),
                                    pkh((f2){Ti4[2], Ti4[3]}) });
            // ---- stage-2: phi^T = B * T, 4x mfma 16x16x16 ----
            f4 Pr4 = mfma16(nBif, Tif, mfma16(Brf, Trf, zz));
            f4 Pi4 = mfma16(Bif,  Trf, mfma16(Brf, Tif, zz));
            // ---- probs + in-lane 4-WHT (over wires 6,7) -> 3 classes ----
            float Q0 = Pr4[0]*Pr4[0] + Pi4[0]*Pi4[0];
            float Q1 = Pr4[1]*Pr4[1] + Pi4[1]*Pi4[1];
            float Q2 = Pr4[2]*Pr4[2] + Pi4[2]*Pi4[2];
            float Q3 = Pr4[3]*Pr4[3] + Pi4[3]*Pi4[3];
            float s01 = Q0 + Q1, s23 = Q2 + Q3;
            float S00 = s01 + s23;
            float S10 = s01 - s23;              // sign by w6
            float S11 = (Q0 - Q1) - (Q2 - Q3);  // sign by w6^w7
            uint2 wv = { pkh((f2){S00, S10}), pkh((f2){S11, 0.f}) };
            *(uint2*)(Rw + s4*544) = wv;
        }
        // ---- epilogue: batched R reads, two independent 4-deep chains ----
        uint4 rv[8];
#pragma unroll
        for (int tt = 0; tt < 8; ++tt) rv[tt] = *(uint4*)(Rr + tt*64);
        f4 acc0 = zz, acc1 = zz;
#pragma unroll
        for (int tt = 0; tt < 4; ++tt) {
            half8 af, ag;
            __builtin_memcpy(&af, &rv[tt],     16);
            __builtin_memcpy(&ag, &rv[tt + 4], 16);
            acc0 = __builtin_amdgcn_mfma_f32_16x16x32_f16(af, sgt[tt*64 + L],       acc0, 0, 0, 0);
            acc1 = __builtin_amdgcn_mfma_f32_16x16x32_f16(ag, sgt[(tt + 4)*64 + L], acc1, 0, 0, 0);
        }
        f4 acc = acc0 + acc1;
        if (hq == 0 && col < 8) {       // rows 0..3 = samples h*4..h*4+3
            size_t base = (size_t)(b0 + h*4) * 8 + col;
            out[base     ] = acc[0];
            out[base +  8] = acc[1];
            out[base + 16] = acc[2];
            out[base + 24] = acc[3];
        }
    }
}

extern "C" void kernel_launch(void* const* d_in, const int* in_sizes, int n_in,
                              void* d_out, int out_size, void* d_ws, size_t ws_size,
                              hipStream_t stream) {
    const float* x = (const float*)d_in[0];
    const float* w = (const float*)d_in[1];
    float* outp    = (float*)d_out;
    float* params  = (float*)d_ws;        // ~12.8 KB used
    int B = in_sizes[0] / 8;

    qnn_setup<<<1, 256, 0, stream>>>(w, params);
    int blocks = (B + 63) / 64;           // 4 waves/block, 16 samples/wave
    qnn_main<<<blocks, 256, 0, stream>>>(x, params, outp, B);
}

// Round 15
// 84.346 us; speedup vs baseline: 1.0029x; 1.0029x over previous
//
#include <hip/hip_runtime.h>
#include <math.h>

// QNN: 8 qubits, DIM=256, 2 entangling layers, B samples.
//  - RX(x_q) fuses with layer-1 RX -> product state v_q (V0,V1).
//  - CNOT ring 1 folded into product expansion; rank-8 split (R7):
//      S[row][col] = RF[row] * TH[(h1,h1^h0)][col0] * cf[col] * V4[col3^r0]
//  - Layer-2: phi = A*S*B^T computed as T = S^T*A^T (= M^T) then phi^T = B*T,
//    using mfma_f32_16x16x16f16 (R12): A/B operand layout == C/D layout, so
//    front-end feeds stage-1 directly and stage-1 feeds stage-2 directly —
//    zero LDS round-trips in the matmul.
//  - CNOT ring 2 + <Z_w> + reduction folded into a constant sign matrix
//    applied as mfma 16x16x32 f16 chain (R6), phi^T bit mapping (R12).
// R15 = R12 with __launch_bounds__(256,8): WAVE_LDS 5120 -> block 20480 ->
//   LDS permits exactly 8 blocks/CU (163840 B); R12's (256,6) was the real
//   occupancy limiter (VGPR target). (256,8) forces <=64 VGPR -> 32 waves/CU,
//   +33% TLP on a latency-bound kernel (issue util ~12% by static count).

typedef float f2 __attribute__((ext_vector_type(2)));
typedef float f4 __attribute__((ext_vector_type(4)));
typedef _Float16 half4 __attribute__((ext_vector_type(4)));
typedef _Float16 half8 __attribute__((ext_vector_type(8)));

// f32 complex mul, 2 VOP3P ops (verified R3-R14) - table-build phase
__device__ __forceinline__ f2 cmul_pk(f2 a, f2 b) {
    f2 t, d;
    asm("v_pk_mul_f32 %0, %1, %2 op_sel:[0,0] op_sel_hi:[0,1]"
        : "=v"(t) : "v"(a), "v"(b));
    asm("v_pk_fma_f32 %0, %1, %2, %3 op_sel:[1,1,0] op_sel_hi:[1,0,1] neg_lo:[1,0,0] neg_hi:[0,0,0]"
        : "=v"(d) : "v"(a), "v"(b), "v"(t));
    return d;
}
// packed-f16 complex mul (verified R9-R14)
__device__ __forceinline__ unsigned cmulh(unsigned a, unsigned b) {
    unsigned t, d;
    asm("v_pk_mul_f16 %0, %1, %2 op_sel:[0,0] op_sel_hi:[0,1]"
        : "=v"(t) : "v"(a), "v"(b));
    asm("v_pk_fma_f16 %0, %1, %2, %3 op_sel:[1,1,0] op_sel_hi:[1,0,1] neg_lo:[1,0,0] neg_hi:[0,0,0]"
        : "=v"(d) : "v"(a), "v"(b), "v"(t));
    return d;
}
__device__ __forceinline__ unsigned pkh(f2 v) {
    auto pk = __builtin_amdgcn_cvt_pkrtz(v.x, v.y);
    unsigned u; __builtin_memcpy(&u, &pk, 4);
    return u;
}
__device__ __forceinline__ half4 h4(uint2 u) {
    half4 h; __builtin_memcpy(&h, &u, 8);
    return h;
}
__device__ __forceinline__ f4 mfma16(half4 a, half4 b, f4 c) {
    return __builtin_amdgcn_mfma_f32_16x16x16f16(a, b, c, 0, 0, 0);
}

// ---------------- setup (identical to R12) ----------------
// d_ws bytes: 0..511 floats (w0 + K-tables);
//   512: S1Ar | 1024: S1Ai | 1536: S1nAi   (A^T in 16x16x16 B-layout, f16)
//   2048: S2Br | 2560: S2Bi | 3072: S2nBi  (B   in 16x16x16 A-layout, f16)
//   4608..12799: sign table SG (f16, 16x16x32 A-layout chunks)
__global__ void qnn_setup(const float* __restrict__ w, float* __restrict__ p) {
    int t = threadIdx.x;
    if (t < 8) {
        int q = t;
        float cb = cosf(w[q*3+1]*0.5f), sb = sinf(w[q*3+1]*0.5f);
        float cg = cosf(w[q*3+2]*0.5f), sg = sinf(w[q*3+2]*0.5f);
        p[q] = w[q*3+0];
        float* K = p + 8 + q*8;
        K[0] = cg*cb;  K[1] = -sg*cb;      // K1
        K[2] = sg*sb;  K[3] = cg*sb;       // K2
        K[4] = cg*sb;  K[5] = sg*sb;       // K3
        K[6] = sg*cb;  K[7] = -cg*cb;      // K4
    }
    float G[8][2][2][2];
    for (int q = 0; q < 8; ++q) {
        const float* wq = w + (8+q)*3;
        float ca = cosf(wq[0]*0.5f), sa = sinf(wq[0]*0.5f);
        float cb = cosf(wq[1]*0.5f), sb = sinf(wq[1]*0.5f);
        float cg = cosf(wq[2]*0.5f), sg = sinf(wq[2]*0.5f);
        float A = cb*ca, Bv = sb*sa, C = sb*ca, D = cb*sa;
        float g00r = cg*A + sg*Bv, g00i = cg*Bv - sg*A;
        float g01r = -(cg*C + sg*D), g01i = sg*C - cg*D;
        G[q][0][0][0]=g00r;  G[q][0][0][1]=g00i;
        G[q][0][1][0]=g01r;  G[q][0][1][1]=g01i;
        G[q][1][0][0]=-g01r; G[q][1][0][1]=g01i;
        G[q][1][1][0]=g00r;  G[q][1][1][1]=-g00i;
    }
    int m = t & 15, k2 = t >> 4;
    float ar = 1.f, ai = 0.f, br = 1.f, bi = 0.f;
    for (int j = 0; j < 4; ++j) {
        int bm = (m >> (3-j)) & 1, bk = (k2 >> (3-j)) & 1;
        float gr = G[j][bm][bk][0],  gi = G[j][bm][bk][1];
        float nr = ar*gr - ai*gi, ni = ar*gi + ai*gr; ar = nr; ai = ni;
        float hr = G[4+j][bm][bk][0], hi = G[4+j][bm][bk][1];
        float mr = br*hr - bi*hi, mi = br*hi + bi*hr; br = mr; bi = mi;
    }
    // element A[m][k2] -> lane l=(k2>>2)*16+m, slot j=k2&3 (same for both
    // the B-layout of A^T and the A-layout of B: idx=lane&15, k=quad*4+j)
    _Float16* S1Ar  = (_Float16*)((char*)p +  512);
    _Float16* S1Ai  = (_Float16*)((char*)p + 1024);
    _Float16* S1nAi = (_Float16*)((char*)p + 1536);
    _Float16* S2Br  = (_Float16*)((char*)p + 2048);
    _Float16* S2Bi  = (_Float16*)((char*)p + 2560);
    _Float16* S2nBi = (_Float16*)((char*)p + 3072);
    int idx = ((k2 >> 2)*16 + m)*4 + (k2 & 3);
    S1Ar[idx]  = (_Float16)ar;
    S1Ai[idx]  = (_Float16)ai;
    S1nAi[idx] = (_Float16)(-ai);
    S2Br[idx]  = (_Float16)br;
    S2Bi[idx]  = (_Float16)bi;
    S2nBi[idx] = (_Float16)(-bi);

    // sign table - phi^T bit assignment (R12, verified):
    // lane = quad*16+col: col = wires0-3 index (wire0 MSB), quad = wires4,5;
    // in-lane r = wires6,7. Classes: c0=S00, c1=S10 (sign w6), c2=S11 (w6^w7).
    const int cls[8] = {2, 0, 0, 0, 0, 0, 1, 2};
    const int msk[8] = {55, 12, 14, 15, 47, 63, 63, 63};
    _Float16* SG = (_Float16*)((char*)p + 4608);
    for (int e = t; e < 512; e += 256) {
        int tt = e >> 6, l = e & 63, n = l & 15, quad = l >> 4;
        for (int j = 0; j < 8; ++j) {
            int k  = tt*32 + quad*8 + j;
            int Lp = k >> 2, c = k & 3;
            float v = 0.f;
            if (n < 8 && c == cls[n])
                v = (__popc(msk[n] & Lp) & 1) ? -1.f : 1.f;
            SG[e*8 + j] = (_Float16)v;
        }
    }
}

// per-wave LDS (5056 B used -> 5120; block 20480 -> exactly 8 blocks/CU):
//   TH 512 | cf 1088 (stride 68) | V4 256 | RF 1024 (stride 64) |
//   R 2176 (4 rows x 544)  [VT 2048 aliased into R, dead before R writes]
#define WAVE_LDS 5120

__global__ __launch_bounds__(256, 8) void qnn_main(
        const float* __restrict__ x, const float* __restrict__ p,
        float* __restrict__ out, int B)
{
    __shared__ __align__(16) char smem[4 * WAVE_LDS];
    const int lane = threadIdx.x & 63;
    const int wid  = threadIdx.x >> 6;
    const int L = lane;
    const int b0 = (blockIdx.x * 4 + wid) * 16;
    if (b0 >= B) return;

    char* wb  = smem + wid * WAVE_LDS;
    char* THb = wb;                     // 512
    char* CFb = wb + 512;               // 1088
    char* V4t = wb + 1600;              // 256
    char* RFb = wb + 1856;              // 1024
    char* Rb  = wb + 2880;              // 2176 (VT alias first)
    f4*   VT  = (f4*)Rb;

    // constant frags (loop-invariant), all f16
    const uint2* ft = (const uint2*)((const char*)p + 512);
    half4 Art  = h4(ft[      L]);
    half4 Ait  = h4(ft[ 64 + L]);
    half4 nAit = h4(ft[128 + L]);
    half4 Brf  = h4(ft[192 + L]);
    half4 Bif  = h4(ft[256 + L]);
    half4 nBif = h4(ft[320 + L]);
    const half8* sgt = (const half8*)((const char*)p + 4608);

    // ---- phase A: build V for 16 samples x 8 qubits (2 builds/lane) ----
    {
        int sI = L >> 2, qp = (L & 3) * 2;
        float2 xv  = ((const float2*)x)[(size_t)(b0 + sI)*4 + (L & 3)];
        float2 w0p = ((const float2*)p)[qp >> 1];
        const f4* Kt = (const f4*)(p + 8);
#pragma unroll
        for (int u = 0; u < 2; ++u) {
            int q = qp + u;
            float ang = (u ? xv.y : xv.x) + (u ? w0p.y : w0p.x);
            float rev = ang * 0.07957747154594767f;      // (ang/2)/(2pi)
            float ca = __builtin_amdgcn_cosf(rev);
            float sa = __builtin_amdgcn_sinf(rev);
            f4 Ka = Kt[q*2], Kb = Kt[q*2+1];
            f4 v;
            v.x = ca*Ka.x + sa*Ka.z;  v.y = ca*Ka.y + sa*Ka.w;   // V0
            v.z = ca*Kb.x + sa*Kb.z;  v.w = ca*Kb.y + sa*Kb.w;   // V1
            VT[sI*8 + q] = v;
        }
    }
    // same-wave LDS is in-order; all regions per-wave -> no barriers

    // ---- phase B: build TH/cf/V4/RF tables in f16 (4 lanes per sample) ----
    {
        int sI = L >> 2, j = L & 3;
        const f4* Vs = VT + sI*8;
        f4 q0v = Vs[0], q1v = Vs[1], q2v = Vs[2], q3v = Vs[3];
        f4 q4v = Vs[4], q5v = Vs[5], q6v = Vs[6], q7v = Vs[7];
        f2 V0a = {q0v.x,q0v.y}, V0b = {q0v.z,q0v.w};
        f2 V1a = {q1v.x,q1v.y}, V1b = {q1v.z,q1v.w};
        f2 V2a = {q2v.x,q2v.y}, V2b = {q2v.z,q2v.w};
        f2 V3a = {q3v.x,q3v.y}, V3b = {q3v.z,q3v.w};
        f2 V4a = {q4v.x,q4v.y}, V4bv = {q4v.z,q4v.w};
        f2 V5a = {q5v.x,q5v.y}, V5b = {q5v.z,q5v.w};
        f2 V6a = {q6v.x,q6v.y}, V6b = {q6v.z,q6v.w};
        f2 V7a = {q7v.x,q7v.y}, V7b = {q7v.z,q7v.w};
        // TH slot j = (t1,t2) = (j>>1, j&1); entries col0 = 0,1  (f16)
        int t1 = j >> 1, t2 = j & 1;
        f2 th0 = cmul_pk(t1 ? V0b : V0a, t2 ? V1b : V1a);
        f2 th1 = cmul_pk(t1 ? V0a : V0b, t2 ? V1a : V1b);
        *(uint2*)(THb + sI*32 + j*8) = (uint2){pkh(th0), pkh(th1)};
        // cf for cols 4j..4j+3 (f16): col3 = j>>1, col2 = j&1
        int col3 = j >> 1, col2 = j & 1;
        f2 v5s  = (col3 ^ col2) ? V5b : V5a;
        f2 p6_0 = cmul_pk(v5s, col2 ? V6b : V6a);     // col1 = 0
        f2 p6_1 = cmul_pk(v5s, col2 ? V6a : V6b);     // col1 = 1
#pragma unroll
        for (int c = 0; c < 4; ++c) {
            int c1 = c >> 1, c0 = c & 1;
            f2 cf = cmul_pk(c1 ? p6_1 : p6_0, (c1 ^ c0) ? V7b : V7a);
            *(unsigned*)(CFb + sI*68 + (4*j + c)*4) = pkh(cf);
        }
        // V4 table: entry[col3] = (V4[col3], V4[1^col3])  (j<2 writes)
        if (j < 2) {
            f2 lo = j ? V4bv : V4a, hi = j ? V4a : V4bv;
            *(uint2*)(V4t + sI*16 + j*8) = (uint2){pkh(lo), pkh(hi)};
        }
        // RF rows 4j..4j+3 (f16): RF[row] = V2[row2^row1]*V3[row1^row0]
        unsigned rr[4];
#pragma unroll
        for (int r = 0; r < 4; ++r) {
            int r1 = r >> 1, r0 = r & 1;
            f2 rf = cmul_pk(((j & 1) ^ r1) ? V2b : V2a, (r1 ^ r0) ? V3b : V3a);
            rr[r] = pkh(rf);
        }
        *(uint4*)(RFb + sI*64 + j*16) = (uint4){rr[0], rr[1], rr[2], rr[3]};
    }

    // ---- hoisted lane constants ----
    const int hq  = L >> 4;             // quad
    const int col = L & 15;
    const int th_t1 = hq >> 1, th_t2 = (hq >> 1) ^ (hq & 1);
    char* THl = THb + ((th_t1*2 + th_t2)*2 + (col & 1))*4;
    char* CFl = CFb + col*4;
    char* V4l = V4t + (col >> 3)*8;
    char* RFl = RFb + hq*16;
    char* Rw  = Rb + L*8;
    char* Rr  = Rb + (col & 3)*544 + hq*16;
    const f4 zz = {0.f, 0.f, 0.f, 0.f};

    for (int h = 0; h < 4; ++h) {
        for (int s4 = 0; s4 < 4; ++s4) {
            const int s = h*4 + s4;
            // ---- front-end (all f16): a_r = RF[4hq+r] * TH * cf * V4 ----
            unsigned u  = *(const unsigned*)(THl + s*32);
            unsigned cf = *(const unsigned*)(CFl + s*68);
            uint2   v4  = *(const uint2*)(V4l + s*16);
            uint4   rf  = *(const uint4*)(RFl + s*64);
            unsigned g  = cmulh(u, cf);
            unsigned gl = cmulh(g, v4.x);
            unsigned gh = cmulh(g, v4.y);
            unsigned a0 = cmulh(rf.x, gl);
            unsigned a1 = cmulh(rf.y, gh);
            unsigned a2 = cmulh(rf.z, gl);
            unsigned a3 = cmulh(rf.w, gh);
            // a_j = S[quad*4+j][col] = S^T A-operand rows; split re/im
            half4 Srf = h4((uint2){ __builtin_amdgcn_perm(a1, a0, 0x05040100u),
                                    __builtin_amdgcn_perm(a3, a2, 0x05040100u) });
            half4 Sif = h4((uint2){ __builtin_amdgcn_perm(a1, a0, 0x07060302u),
                                    __builtin_amdgcn_perm(a3, a2, 0x07060302u) });
            // ---- stage-1: T = S^T * A^T  (= M^T), 4x mfma 16x16x16 ----
            f4 Tr4 = mfma16(Sif, nAit, mfma16(Srf, Art, zz));
            f4 Ti4 = mfma16(Sif, Art,  mfma16(Srf, Ait, zz));
            // C layout == B-operand layout: pack rows quad*4+r to f16
            half4 Trf = h4((uint2){ pkh((f2){Tr4[0], Tr4[1]}),
                                    pkh((f2){Tr4[2], Tr4[3]}) });
            half4 Tif = h4((uint2){ pkh((f2){Ti4[0], Ti4[1]}),
                                    pkh((f2){Ti4[2], Ti4[3]}) });
            // ---- stage-2: phi^T = B * T, 4x mfma 16x16x16 ----
            f4 Pr4 = mfma16(nBif, Tif, mfma16(Brf, Trf, zz));
            f4 Pi4 = mfma16(Bif,  Trf, mfma16(Brf, Tif, zz));
            // ---- probs + in-lane 4-WHT (over wires 6,7) -> 3 classes ----
            float Q0 = Pr4[0]*Pr4[0] + Pi4[0]*Pi4[0];
            float Q1 = Pr4[1]*Pr4[1] + Pi4[1]*Pi4[1];
            float Q2 = Pr4[2]*Pr4[2] + Pi4[2]*Pi4[2];
            float Q3 = Pr4[3]*Pr4[3] + Pi4[3]*Pi4[3];
            float s01 = Q0 + Q1, s23 = Q2 + Q3;
            float S00 = s01 + s23;
            float S10 = s01 - s23;              // sign by w6
            float S11 = (Q0 - Q1) - (Q2 - Q3);  // sign by w6^w7
            uint2 wv = { pkh((f2){S00, S10}), pkh((f2){S11, 0.f}) };
            *(uint2*)(Rw + s4*544) = wv;
        }
        // ---- epilogue: out[s][w] = R x Sgn (8 chained f16 MFMAs) ----
        f4 acc = zz;
#pragma unroll
        for (int tt = 0; tt < 8; ++tt) {
            uint4 rv = *(uint4*)(Rr + tt*64);
            half8 af;
            __builtin_memcpy(&af, &rv, 16);
            acc = __builtin_amdgcn_mfma_f32_16x16x32_f16(af, sgt[tt*64 + L], acc, 0, 0, 0);
        }
        if (hq == 0 && col < 8) {       // rows 0..3 = samples h*4..h*4+3
            size_t base = (size_t)(b0 + h*4) * 8 + col;
            out[base     ] = acc[0];
            out[base +  8] = acc[1];
            out[base + 16] = acc[2];
            out[base + 24] = acc[3];
        }
    }
}

extern "C" void kernel_launch(void* const* d_in, const int* in_sizes, int n_in,
                              void* d_out, int out_size, void* d_ws, size_t ws_size,
                              hipStream_t stream) {
    const float* x = (const float*)d_in[0];
    const float* w = (const float*)d_in[1];
    float* outp    = (float*)d_out;
    float* params  = (float*)d_ws;        // ~12.8 KB used
    int B = in_sizes[0] / 8;

    qnn_setup<<<1, 256, 0, stream>>>(w, params);
    int blocks = (B + 63) / 64;           // 4 waves/block, 16 samples/wave
    qnn_main<<<blocks, 256, 0, stream>>>(x, params, outp, B);
}

// Round 16
// 80.170 us; speedup vs baseline: 1.0551x; 1.0521x over previous
//
#include <hip/hip_runtime.h>
#include <math.h>

// QNN: 8 qubits, DIM=256, 2 entangling layers, B samples.
//  - RX(x_q) fuses with layer-1 RX -> product state v_q (V0,V1).
//  - CNOT ring 1 folded into product expansion; rank-8 split (R7/R9):
//      S[row][col] = RF[row] * TH[(h1,h1^h0)][col0] * TC[col][r0]
//  - Layer-2: phi = A*S*B^T computed as T = S^T*A^T then phi^T = B*T with
//    mfma_f32_16x16x16f16 (R12): operand layout == C/D layout, zero LDS
//    round-trips in the matmul.
//  - CNOT ring 2 + <Z_w> + reduction folded into a constant sign matrix
//    applied as mfma 16x16x32 f16 chain (R6), phi^T bit mapping (R12).
// R16: SINGLE-KERNEL fusion (R13 math, byte-identical loop):
//    - A/B gate frags computed per-lane in-kernel (one-time ~400cyc/wave;
//      lane mapping == setup's idx=((k2>>2)*16+m)*4+(k2&3), gate-k bits
//      q1,q0,j1,j0 verified).
//    - layer-1 K tables inlined into phase A (hw trig).
//    - sign table is input-independent -> constexpr device array.
//    Removes the qnn_setup dispatch + graph dependency edge; d_ws unused.

typedef float f2 __attribute__((ext_vector_type(2)));
typedef float f4 __attribute__((ext_vector_type(4)));
typedef _Float16 half4 __attribute__((ext_vector_type(4)));
typedef _Float16 half8 __attribute__((ext_vector_type(8)));

// f32 complex mul, 2 VOP3P ops (verified R3-R15)
__device__ __forceinline__ f2 cmul_pk(f2 a, f2 b) {
    f2 t, d;
    asm("v_pk_mul_f32 %0, %1, %2 op_sel:[0,0] op_sel_hi:[0,1]"
        : "=v"(t) : "v"(a), "v"(b));
    asm("v_pk_fma_f32 %0, %1, %2, %3 op_sel:[1,1,0] op_sel_hi:[1,0,1] neg_lo:[1,0,0] neg_hi:[0,0,0]"
        : "=v"(d) : "v"(a), "v"(b), "v"(t));
    return d;
}
// packed-f16 complex mul (verified R9-R15)
__device__ __forceinline__ unsigned cmulh(unsigned a, unsigned b) {
    unsigned t, d;
    asm("v_pk_mul_f16 %0, %1, %2 op_sel:[0,0] op_sel_hi:[0,1]"
        : "=v"(t) : "v"(a), "v"(b));
    asm("v_pk_fma_f16 %0, %1, %2, %3 op_sel:[1,1,0] op_sel_hi:[1,0,1] neg_lo:[1,0,0] neg_hi:[0,0,0]"
        : "=v"(d) : "v"(a), "v"(b), "v"(t));
    return d;
}
__device__ __forceinline__ unsigned pkh(f2 v) {
    auto pk = __builtin_amdgcn_cvt_pkrtz(v.x, v.y);
    unsigned u; __builtin_memcpy(&u, &pk, 4);
    return u;
}
__device__ __forceinline__ half4 h4(uint2 u) {
    half4 h; __builtin_memcpy(&h, &u, 8);
    return h;
}
__device__ __forceinline__ f4 mfma16(half4 a, half4 b, f4 c) {
    return __builtin_amdgcn_mfma_f32_16x16x16f16(a, b, c, 0, 0, 0);
}

// SU(2) gate-entry select: G[r][c] from first row (g00,g01);
// G[1][0] = -conj(g01), G[1][1] = conj(g00)   (matches R12 setup table)
__device__ __forceinline__ f2 gsel(const float* g, int r, int c) {
    f2 e0 = c ? (f2){g[2],  g[3]} : (f2){ g[0], g[1]};
    f2 e1 = c ? (f2){g[0], -g[1]} : (f2){-g[2], g[3]};
    return r ? e1 : e0;
}

// ---- constexpr sign table (input-independent; R12 phi^T bit mapping) ----
struct SgTab { unsigned short v[4096]; };
constexpr int cpop(int x) { int c = 0; while (x) { c += x & 1; x >>= 1; } return c; }
constexpr SgTab make_sg() {
    SgTab t{};
    const int cls[8] = {2, 0, 0, 0, 0, 0, 1, 2};
    const int msk[8] = {55, 12, 14, 15, 47, 63, 63, 63};
    for (int e = 0; e < 512; ++e) {
        int tt = e >> 6, l = e & 63, n = l & 15, quad = l >> 4;
        for (int j = 0; j < 8; ++j) {
            int k = tt*32 + quad*8 + j;
            int Lp = k >> 2, c = k & 3;
            unsigned short hv = 0;                      // f16 0.0
            if (n < 8 && c == cls[n])
                hv = (cpop(msk[n] & Lp) & 1) ? 0xBC00 : 0x3C00;  // -1 : +1
            t.v[e*8 + j] = hv;
        }
    }
    return t;
}
__device__ constexpr SgTab SG = make_sg();

// per-wave LDS (5888 B -> 6144; block 24576 -> 6 blocks/CU), R13 layout:
//   TH 512 | TC 2176 (stride 136) | RF 1024 (stride 64) |
//   R 2176 (4 rows x 544)  [VT 2048 aliased into R, dead before R writes]
#define WAVE_LDS 6144

__global__ __launch_bounds__(256, 6) void qnn_main(
        const float* __restrict__ x, const float* __restrict__ w,
        float* __restrict__ out, int B)
{
    __shared__ __align__(16) char smem[4 * WAVE_LDS];
    const int lane = threadIdx.x & 63;
    const int wid  = threadIdx.x >> 6;
    const int L = lane;
    const int b0 = (blockIdx.x * 4 + wid) * 16;
    if (b0 >= B) return;

    char* wb  = smem + wid * WAVE_LDS;
    char* THb = wb;                     // 512
    char* TCb = wb + 512;               // 2176
    char* RFb = wb + 2688;              // 1024
    char* Rb  = wb + 3712;              // 2176 (VT alias first)
    f4*   VT  = (f4*)Rb;

    const float CREV = 0.07957747154594767f;   // 0.5/(2*pi)
    const int hq  = L >> 4;             // quad
    const int col = L & 15;

    // ---- one-time per-lane frag build (layer-2 gate tensor products) ----
    // lane (hq,col) holds X[col][k2], k2 = hq*4+j: gate-k bits q1,q0,j1,j0
    half4 Art, Ait, nAit, Brf, Bif, nBif;
    {
        const int mb0 = (col>>3)&1, mb1 = (col>>2)&1, mb2 = (col>>1)&1, mb3 = col&1;
        const int q1 = (hq>>1)&1, q0 = hq&1;
        float gv[4][4];
#pragma unroll
        for (int half = 0; half < 2; ++half) {
#pragma unroll
            for (int q = 0; q < 4; ++q) {
                const float* wq = w + (8 + half*4 + q)*3;
                float ra = wq[0]*CREV, rb = wq[1]*CREV, rg = wq[2]*CREV;
                float ca = __builtin_amdgcn_cosf(ra), sa = __builtin_amdgcn_sinf(ra);
                float cb = __builtin_amdgcn_cosf(rb), sb = __builtin_amdgcn_sinf(rb);
                float cg = __builtin_amdgcn_cosf(rg), sg = __builtin_amdgcn_sinf(rg);
                float A = cb*ca, Bv = sb*sa, Cc = sb*ca, D = cb*sa;
                gv[q][0] = cg*A + sg*Bv;        // g00r
                gv[q][1] = cg*Bv - sg*A;        // g00i
                gv[q][2] = -(cg*Cc + sg*D);     // g01r
                gv[q][3] = sg*Cc - cg*D;        // g01i
            }
            f2 P01 = cmul_pk(gsel(gv[0], mb0, q1), gsel(gv[1], mb1, q0));
            f2 Xj[4];
#pragma unroll
            for (int j = 0; j < 4; ++j)
                Xj[j] = cmul_pk(P01, cmul_pk(gsel(gv[2], mb2, j>>1),
                                             gsel(gv[3], mb3, j&1)));
            half4 Xr = h4((uint2){ pkh((f2){Xj[0].x, Xj[1].x}),
                                   pkh((f2){Xj[2].x, Xj[3].x}) });
            half4 Xi = h4((uint2){ pkh((f2){Xj[0].y, Xj[1].y}),
                                   pkh((f2){Xj[2].y, Xj[3].y}) });
            half4 Xn = h4((uint2){ pkh((f2){-Xj[0].y, -Xj[1].y}),
                                   pkh((f2){-Xj[2].y, -Xj[3].y}) });
            if (half == 0) { Art = Xr; Ait = Xi; nAit = Xn; }
            else           { Brf = Xr; Bif = Xi; nBif = Xn; }
        }
    }
    const half8* sgt = (const half8*)SG.v;

    // ---- phase A: build V for 16 samples x 8 qubits (2 builds/lane) ----
    // K tables inlined: V0 = (ca*cg*cb + sa*sg*sb, sa*cg*sb - ca*sg*cb)
    //                   V1 = (ca*cg*sb + sa*sg*cb, ca*sg*sb - sa*cg*cb)
    {
        int sI = L >> 2, qp = (L & 3) * 2;
        float2 xv = ((const float2*)x)[(size_t)(b0 + sI)*4 + (L & 3)];
#pragma unroll
        for (int u = 0; u < 2; ++u) {
            int q = qp + u;
            float w0 = w[q*3+0], w1 = w[q*3+1], w2 = w[q*3+2];
            float ang = (u ? xv.y : xv.x) + w0;
            float ra = ang * CREV, rb = w1 * CREV, rg = w2 * CREV;
            float ca = __builtin_amdgcn_cosf(ra), sa = __builtin_amdgcn_sinf(ra);
            float cb = __builtin_amdgcn_cosf(rb), sb = __builtin_amdgcn_sinf(rb);
            float cg = __builtin_amdgcn_cosf(rg), sg = __builtin_amdgcn_sinf(rg);
            f4 v;
            v.x = ca*(cg*cb) + sa*(sg*sb);
            v.y = sa*(cg*sb) - ca*(sg*cb);
            v.z = ca*(cg*sb) + sa*(sg*cb);
            v.w = ca*(sg*sb) - sa*(cg*cb);
            VT[sI*8 + q] = v;
        }
    }
    // same-wave LDS is in-order; all regions per-wave -> no barriers

    // ---- phase B: build TH/TC/RF tables in f16 (4 lanes per sample) ----
    {
        int sI = L >> 2, j = L & 3;
        const f4* Vs = VT + sI*8;
        f4 q0v = Vs[0], q1v = Vs[1], q2v = Vs[2], q3v = Vs[3];
        f4 q4v = Vs[4], q5v = Vs[5], q6v = Vs[6], q7v = Vs[7];
        f2 V0a = {q0v.x,q0v.y}, V0b = {q0v.z,q0v.w};
        f2 V1a = {q1v.x,q1v.y}, V1b = {q1v.z,q1v.w};
        f2 V2a = {q2v.x,q2v.y}, V2b = {q2v.z,q2v.w};
        f2 V3a = {q3v.x,q3v.y}, V3b = {q3v.z,q3v.w};
        f2 V4a = {q4v.x,q4v.y}, V4bv = {q4v.z,q4v.w};
        f2 V5a = {q5v.x,q5v.y}, V5b = {q5v.z,q5v.w};
        f2 V6a = {q6v.x,q6v.y}, V6b = {q6v.z,q6v.w};
        f2 V7a = {q7v.x,q7v.y}, V7b = {q7v.z,q7v.w};
        // TH slot j = (t1,t2) = (j>>1, j&1); entries col0 = 0,1  (f16)
        int t1 = j >> 1, t2 = j & 1;
        f2 th0 = cmul_pk(t1 ? V0b : V0a, t2 ? V1b : V1a);
        f2 th1 = cmul_pk(t1 ? V0a : V0b, t2 ? V1a : V1b);
        *(uint2*)(THb + sI*32 + j*8) = (uint2){pkh(th0), pkh(th1)};
        // TC cols 4j..4j+3 (f16): col3 = j>>1, col2 = j&1 (R9 layout)
        int col3 = j >> 1, col2 = j & 1;
        f2 v5s  = (col3 ^ col2) ? V5b : V5a;
        f2 p6_0 = cmul_pk(v5s, col2 ? V6b : V6a);     // col1 = 0
        f2 p6_1 = cmul_pk(v5s, col2 ? V6a : V6b);     // col1 = 1
        f2 V4lo = col3 ? V4bv : V4a;                  // V4[col3]     (r0=0)
        f2 V4hi = col3 ? V4a : V4bv;                  // V4[1^col3]   (r0=1)
#pragma unroll
        for (int c = 0; c < 4; ++c) {
            int c1 = c >> 1, c0 = c & 1;
            f2 cf = cmul_pk(c1 ? p6_1 : p6_0, (c1 ^ c0) ? V7b : V7a);
            f2 e0 = cmul_pk(cf, V4lo);
            f2 e1 = cmul_pk(cf, V4hi);
            *(uint2*)(TCb + sI*136 + (4*j + c)*8) = (uint2){pkh(e0), pkh(e1)};
        }
        // RF rows 4j..4j+3 (f16): RF[row] = V2[row2^row1]*V3[row1^row0]
        unsigned rr[4];
#pragma unroll
        for (int r = 0; r < 4; ++r) {
            int r1 = r >> 1, r0 = r & 1;
            f2 rf = cmul_pk(((j & 1) ^ r1) ? V2b : V2a, (r1 ^ r0) ? V3b : V3a);
            rr[r] = pkh(rf);
        }
        *(uint4*)(RFb + sI*64 + j*16) = (uint4){rr[0], rr[1], rr[2], rr[3]};
    }

    // ---- hoisted lane constants ----
    const int th_t1 = hq >> 1, th_t2 = (hq >> 1) ^ (hq & 1);
    char* THl = THb + ((th_t1*2 + th_t2)*2 + (col & 1))*4;
    char* TCl = TCb + col*8;
    char* RFl = RFb + hq*16;
    char* Rw  = Rb + L*8;
    char* Rr  = Rb + (col & 3)*544 + hq*16;
    const f4 zz = {0.f, 0.f, 0.f, 0.f};

    for (int h = 0; h < 4; ++h) {
#pragma unroll
        for (int s4 = 0; s4 < 4; ++s4) {
            const int s = h*4 + s4;
            // ---- front-end (R9 form): a_r = RF[4hq+r] * (TH*TC[col][r&1]) --
            unsigned u  = *(const unsigned*)(THl + s*32);
            uint2   tc  = *(const uint2*)(TCl + s*136);
            uint4   rf  = *(const uint4*)(RFl + s*64);
            unsigned g0 = cmulh(u, tc.x);
            unsigned g1 = cmulh(u, tc.y);
            unsigned a0 = cmulh(rf.x, g0);
            unsigned a1 = cmulh(rf.y, g1);
            unsigned a2 = cmulh(rf.z, g0);
            unsigned a3 = cmulh(rf.w, g1);
            // a_j = S[quad*4+j][col] = S^T A-operand rows; split re/im
            half4 Srf = h4((uint2){ __builtin_amdgcn_perm(a1, a0, 0x05040100u),
                                    __builtin_amdgcn_perm(a3, a2, 0x05040100u) });
            half4 Sif = h4((uint2){ __builtin_amdgcn_perm(a1, a0, 0x07060302u),
                                    __builtin_amdgcn_perm(a3, a2, 0x07060302u) });
            // ---- stage-1: T = S^T * A^T  (= M^T), 4x mfma 16x16x16 ----
            f4 Tr4 = mfma16(Sif, nAit, mfma16(Srf, Art, zz));
            f4 Ti4 = mfma16(Sif, Art,  mfma16(Srf, Ait, zz));
            half4 Trf = h4((uint2){ pkh((f2){Tr4[0], Tr4[1]}),
                                    pkh((f2){Tr4[2], Tr4[3]}) });
            half4 Tif = h4((uint2){ pkh((f2){Ti4[0], Ti4[1]}),
                                    pkh((f2){Ti4[2], Ti4[3]}) });
            // ---- stage-2: phi^T = B * T, 4x mfma 16x16x16 ----
            f4 Pr4 = mfma16(nBif, Tif, mfma16(Brf, Trf, zz));
            f4 Pi4 = mfma16(Bif,  Trf, mfma16(Brf, Tif, zz));
            // ---- probs + in-lane 4-WHT (over wires 6,7) -> 3 classes ----
            float Q0 = Pr4[0]*Pr4[0] + Pi4[0]*Pi4[0];
            float Q1 = Pr4[1]*Pr4[1] + Pi4[1]*Pi4[1];
            float Q2 = Pr4[2]*Pr4[2] + Pi4[2]*Pi4[2];
            float Q3 = Pr4[3]*Pr4[3] + Pi4[3]*Pi4[3];
            float s01 = Q0 + Q1, s23 = Q2 + Q3;
            float S00 = s01 + s23;
            float S10 = s01 - s23;              // sign by w6
            float S11 = (Q0 - Q1) - (Q2 - Q3);  // sign by w6^w7
            uint2 wv = { pkh((f2){S00, S10}), pkh((f2){S11, 0.f}) };
            *(uint2*)(Rw + s4*544) = wv;
        }
        // ---- epilogue: out[s][w] = R x Sgn (8 chained f16 MFMAs) ----
        f4 acc = zz;
#pragma unroll
        for (int tt = 0; tt < 8; ++tt) {
            uint4 rv = *(uint4*)(Rr + tt*64);
            half8 af;
            __builtin_memcpy(&af, &rv, 16);
            acc = __builtin_amdgcn_mfma_f32_16x16x32_f16(af, sgt[tt*64 + L], acc, 0, 0, 0);
        }
        if (hq == 0 && col < 8) {       // rows 0..3 = samples h*4..h*4+3
            size_t base = (size_t)(b0 + h*4) * 8 + col;
            out[base     ] = acc[0];
            out[base +  8] = acc[1];
            out[base + 16] = acc[2];
            out[base + 24] = acc[3];
        }
    }
}

extern "C" void kernel_launch(void* const* d_in, const int* in_sizes, int n_in,
                              void* d_out, int out_size, void* d_ws, size_t ws_size,
                              hipStream_t stream) {
    const float* x = (const float*)d_in[0];
    const float* w = (const float*)d_in[1];
    float* outp    = (float*)d_out;
    int B = in_sizes[0] / 8;

    int blocks = (B + 63) / 64;           // 4 waves/block, 16 samples/wave
    qnn_main<<<blocks, 256, 0, stream>>>(x, w, outp, B);
}